// Round 17
// baseline (223.720 us; speedup 1.0000x reference)
//
#include <hip/hip_runtime.h>
#include <hip/hip_bf16.h>

// SIREN + Fourier-features fused forward, MI355X (gfx950). Round 17.
// = round 16 (192.5us best) + critical-path hoists:
//  (a) per-layer bias loads (acc C-in init) issued BEFORE bar1 — their
//      global-load latency is covered by the barrier wait instead of
//      serializing ahead of kt=0's first MFMA;
//  (b) final-layer Wf fragment loads issued BEFORE the last barrier.
// No structural or numerical change (structure ledger: r7-r15 all regressed).

typedef __attribute__((ext_vector_type(8))) short bf16x8;
typedef __attribute__((ext_vector_type(4))) float f32x4;

#define NTOTAL 262144
#define BM 64
#define HD 256
#define INV2PI 0.15915494309189535f

__device__ __forceinline__ unsigned short f2bf(float f) {
    unsigned int u = __float_as_uint(f);
    u += 0x7FFFu + ((u >> 16) & 1u);   // RNE (convert kernel only)
    return (unsigned short)(u >> 16);
}

// pack two floats -> 2xbf16 in one u32 (low = a, high = b), compiler-backed
__device__ __forceinline__ unsigned int pk2(float a, float b) {
    __hip_bfloat162 h = __float22bfloat162_rn(make_float2(a, b));
    union { __hip_bfloat162 h; unsigned int u; } c;
    c.h = h;
    return c.u;
}

// swizzled byte offset into the [64][256] bf16 LDS tile (row stride 512B).
// XOR spans bits 4-7: bijective per row; write conflicts 2-way (free).
__device__ __forceinline__ int a_off(int r, int byte) {
    return r * 512 + (byte ^ ((r & 15) << 4));
}

// ---------------- kernel 1: weight conversion + fragment packing ----------------
// wb (bf16 elems): 5 layers x 65536 fragment-packed W' (pre-scaled by omega/2pi;
// layer0 also x sqrt2), then Wf row-major 16x256 zero-pad (elems 327680..331775),
// then 5x256 f32 scaled biases b' at byte offset 663552.
__global__ void convert_w(const float* __restrict__ W0, const float* __restrict__ Wh,
                          const float* __restrict__ Wf, const float* __restrict__ b0,
                          const float* __restrict__ bh, unsigned short* __restrict__ wb) {
    const int i = blockIdx.x * 256 + threadIdx.x;      // grid 1280 -> 327680
    if (i < 327680) {
        const int l = i >> 16, rem = i & 65535;
        const int j = rem >> 8, k = rem & 255;
        const float sc = (l == 0) ? (1.41421356237309515f * 30.0f * INV2PI) : INV2PI;
        const float v = ((l == 0) ? W0[rem] : Wh[i - 65536]) * sc;
        const int jt = j >> 4, kt = k >> 5, q = (k >> 3) & 3, r = j & 15, t = k & 7;
        const int dst = (l << 16) + (((jt << 3) + kt) << 9) + (((q << 4) + r) << 3) + t;
        wb[dst] = f2bf(v);
    }
    if (i < 4096)
        wb[327680 + i] = (i < 512) ? f2bf(Wf[i]) : (unsigned short)0;
    if (i < 1280) {   // scaled bias table (f32)
        const int l = i >> 8, j = i & 255;
        const float sc = (l == 0) ? (30.0f * INV2PI) : INV2PI;
        float* bsc = (float*)(wb + 331776);
        bsc[i] = ((l == 0) ? b0[j] : bh[i - 256]) * sc;
    }
}

// ---------------- kernel 2: fused model ----------------
__global__ __launch_bounds__(256, 3) void siren_fused(
    const float* __restrict__ x, const float* __restrict__ scales,
    const float* __restrict__ Bm, const float* __restrict__ bfin,
    const unsigned short* __restrict__ wb, float* __restrict__ out) {

    __shared__ __align__(16) unsigned short A[BM * HD];

    const int tid  = threadIdx.x;
    const int lane = tid & 63;
    const int wid  = tid >> 6;          // wave 0..3 owns neurons wid*64..+63
    const int row0 = blockIdx.x * BM;
    const int arow = lane & 15;
    const int q    = lane >> 4;         // 0..3
    const int kq   = q * 8;
    const float* bsc = (const float*)(wb + 331776);

    // ---- preload layer-0 kt=0 W fragments + layer-0 bias (overlap Fourier) ----
    bf16x8 wfbuf[2][4];
    float4 bv[4];
    #pragma unroll
    for (int jt = 0; jt < 4; ++jt) {
        wfbuf[0][jt] = *(const bf16x8*)(wb + (((wid * 4 + jt) << 3) << 9) + lane * 8);
        bv[jt] = *(const float4*)(bsc + wid * 64 + jt * 16 + q * 4);
    }

    // ---- Fourier feature stage (fp32; sqrt2 folded into W0'; no fract) ----
    {
        const int r  = tid >> 2;            // 0..63
        const int c0 = (tid & 3) * 32;      // 32 freqs per thread
        const float* xr = x + (row0 + r) * 3;
        const float x0 = xr[0] * scales[0] * INV2PI;
        const float x1 = xr[1] * scales[1] * INV2PI;
        const float x2 = xr[2] * scales[2] * INV2PI;
        #pragma unroll
        for (int cc = 0; cc < 32; cc += 8) {
            const int c = c0 + cc;
            float sv[8], cv[8];
            #pragma unroll
            for (int t = 0; t < 8; ++t) {
                const float rev = x0 * Bm[c + t] + x1 * Bm[128 + c + t] + x2 * Bm[256 + c + t];
                sv[t] = __builtin_amdgcn_sinf(rev);   // |rev| < ~50 rev, in-domain
                cv[t] = __builtin_amdgcn_cosf(rev);
            }
            uint4 us, uc;
            us.x = pk2(sv[0], sv[1]); us.y = pk2(sv[2], sv[3]);
            us.z = pk2(sv[4], sv[5]); us.w = pk2(sv[6], sv[7]);
            uc.x = pk2(cv[0], cv[1]); uc.y = pk2(cv[2], cv[3]);
            uc.z = pk2(cv[4], cv[5]); uc.w = pk2(cv[6], cv[7]);
            *(uint4*)((char*)A + a_off(r, 2 * c))         = us;
            *(uint4*)((char*)A + a_off(r, 2 * (c + 128))) = uc;
        }
    }

    // ---- 5 dense layers ----
    #pragma unroll 1
    for (int layer = 0; layer < 5; ++layer) {
        const unsigned short* Wl = wb + (layer << 16);

        __syncthreads();   // h tile ready (bias bv[] already in flight/regs)

        // acc initialized with the scaled bias (C-in = b')
        f32x4 acc[4][4];
        #pragma unroll
        for (int jt = 0; jt < 4; ++jt)
            #pragma unroll
            for (int rt = 0; rt < 4; ++rt) {
                acc[jt][rt][0] = bv[jt].x; acc[jt][rt][1] = bv[jt].y;
                acc[jt][rt][2] = bv[jt].z; acc[jt][rt][3] = bv[jt].w;
            }

        #pragma unroll
        for (int kt = 0; kt < 8; ++kt) {
            const int cur = kt & 1, nxt = cur ^ 1;
            bf16x8 hf[4];
            #pragma unroll
            for (int rt = 0; rt < 4; ++rt)
                hf[rt] = *(const bf16x8*)((const char*)A +
                    a_off(rt * 16 + arow, kt * 64 + q * 16));
            if (kt < 7) {
                #pragma unroll
                for (int jt = 0; jt < 4; ++jt)
                    wfbuf[nxt][jt] = *(const bf16x8*)(Wl +
                        ((((wid * 4 + jt) << 3) + kt + 1) << 9) + lane * 8);
            }
            #pragma unroll
            for (int jt = 0; jt < 4; ++jt)
                #pragma unroll
                for (int rt = 0; rt < 4; ++rt)
                    acc[jt][rt] = __builtin_amdgcn_mfma_f32_16x16x32_bf16(
                        wfbuf[cur][jt], hf[rt], acc[jt][rt], 0, 0, 0);
        }

        __syncthreads();   // all reads of h done; safe to overwrite

        // prefetch next layer's kt=0 W fragments + next bias (overlaps epilogue)
        if (layer < 4) {
            const unsigned short* Wn = wb + ((layer + 1) << 16);
            const float* bn = bsc + (layer + 1) * HD;
            #pragma unroll
            for (int jt = 0; jt < 4; ++jt) {
                wfbuf[0][jt] = *(const bf16x8*)(Wn + (((wid * 4 + jt) << 3) << 9) + lane * 8);
                bv[jt] = *(const float4*)(bn + wid * 64 + jt * 16 + q * 4);
            }
        }

        // epilogue: h = sin(2*pi*acc) — bare v_sin + pack (bias/scale pre-folded)
        #pragma unroll
        for (int jt = 0; jt < 4; ++jt) {
            const int jj = wid * 64 + jt * 16 + q * 4;   // 4 consecutive neurons
            #pragma unroll
            for (int rt = 0; rt < 4; ++rt) {
                const int r = rt * 16 + arow;
                const float s0 = __builtin_amdgcn_sinf(acc[jt][rt][0]);
                const float s1 = __builtin_amdgcn_sinf(acc[jt][rt][1]);
                const float s2 = __builtin_amdgcn_sinf(acc[jt][rt][2]);
                const float s3 = __builtin_amdgcn_sinf(acc[jt][rt][3]);
                uint2 val;
                val.x = pk2(s0, s1);
                val.y = pk2(s2, s3);
                *(uint2*)((char*)A + a_off(r, jj * 2)) = val;
            }
        }
    }

    // ---- final linear 256 -> 2: prefetch Wf fragments BEFORE the barrier ----
    {
        const unsigned short* Wfp = wb + 327680;   // row-major [16][256], zero-padded
        bf16x8 ff[8];
        #pragma unroll
        for (int kt = 0; kt < 8; ++kt)
            ff[kt] = *(const bf16x8*)(Wfp + arow * HD + kt * 32 + kq);

        __syncthreads();   // final h ready (ff loads in flight across the wait)

        f32x4 acc = (f32x4)(0.0f);
        #pragma unroll
        for (int kt = 0; kt < 8; ++kt) {
            const bf16x8 hf = *(const bf16x8*)((const char*)A +
                a_off(wid * 16 + arow, kt * 64 + q * 16));
            acc = __builtin_amdgcn_mfma_f32_16x16x32_bf16(ff[kt], hf, acc, 0, 0, 0);
        }
        if (q == 0) {   // lanes 0-15 hold D rows j=0..3; j=0,1 are the two outputs
            const int rg = row0 + wid * 16 + arow;
            float2 o;
            o.x = acc[0] + bfin[0];
            o.y = acc[1] + bfin[1];
            *(float2*)(out + rg * 2) = o;
        }
    }
}

extern "C" void kernel_launch(void* const* d_in, const int* in_sizes, int n_in,
                              void* d_out, int out_size, void* d_ws, size_t ws_size,
                              hipStream_t stream) {
    (void)in_sizes; (void)n_in; (void)out_size; (void)ws_size;
    const float* x      = (const float*)d_in[0];
    const float* scales = (const float*)d_in[1];
    const float* Bm     = (const float*)d_in[2];
    const float* W0     = (const float*)d_in[3];
    const float* b0     = (const float*)d_in[4];
    const float* Wh     = (const float*)d_in[5];
    const float* bh     = (const float*)d_in[6];
    const float* Wf     = (const float*)d_in[7];
    const float* bf     = (const float*)d_in[8];
    unsigned short* wb  = (unsigned short*)d_ws;   // needs 668672 B

    hipLaunchKernelGGL(convert_w, dim3(1280), dim3(256), 0, stream,
                       W0, Wh, Wf, b0, bh, wb);
    hipLaunchKernelGGL(siren_fused, dim3(NTOTAL / BM), dim3(256), 0, stream,
                       x, scales, Bm, bf, wb, (float*)d_out);
}

// Round 18
// 191.694 us; speedup vs baseline: 1.1671x; 1.1671x over previous
//
#include <hip/hip_runtime.h>
#include <hip/hip_bf16.h>

// SIREN + Fourier-features fused forward, MI355X (gfx950). Round 18.
// = round 16 (192.5us best; r17's hoists reverted — they spilled: WRITE 92MB).
// ONE change vs r16: the next-layer W prefetch moved from after bar2 to
// before bar2. Loads are global->reg (no LDS interaction, read-only data),
// so crossing the barrier is safe; latency now overlaps barrier-wait +
// epilogue. Zero new live state (wfbuf[0] is free after kt=6; bias loads
// stay in their proven r16 position after bar1).

typedef __attribute__((ext_vector_type(8))) short bf16x8;
typedef __attribute__((ext_vector_type(4))) float f32x4;

#define NTOTAL 262144
#define BM 64
#define HD 256
#define INV2PI 0.15915494309189535f

__device__ __forceinline__ unsigned short f2bf(float f) {
    unsigned int u = __float_as_uint(f);
    u += 0x7FFFu + ((u >> 16) & 1u);   // RNE (convert kernel only)
    return (unsigned short)(u >> 16);
}

// pack two floats -> 2xbf16 in one u32 (low = a, high = b), compiler-backed
__device__ __forceinline__ unsigned int pk2(float a, float b) {
    __hip_bfloat162 h = __float22bfloat162_rn(make_float2(a, b));
    union { __hip_bfloat162 h; unsigned int u; } c;
    c.h = h;
    return c.u;
}

// swizzled byte offset into the [64][256] bf16 LDS tile (row stride 512B).
// XOR spans bits 4-7: bijective per row; write conflicts 2-way (free).
__device__ __forceinline__ int a_off(int r, int byte) {
    return r * 512 + (byte ^ ((r & 15) << 4));
}

// ---------------- kernel 1: weight conversion + fragment packing ----------------
// wb (bf16 elems): 5 layers x 65536 fragment-packed W' (pre-scaled by omega/2pi;
// layer0 also x sqrt2), then Wf row-major 16x256 zero-pad (elems 327680..331775),
// then 5x256 f32 scaled biases b' at byte offset 663552.
__global__ void convert_w(const float* __restrict__ W0, const float* __restrict__ Wh,
                          const float* __restrict__ Wf, const float* __restrict__ b0,
                          const float* __restrict__ bh, unsigned short* __restrict__ wb) {
    const int i = blockIdx.x * 256 + threadIdx.x;      // grid 1280 -> 327680
    if (i < 327680) {
        const int l = i >> 16, rem = i & 65535;
        const int j = rem >> 8, k = rem & 255;
        const float sc = (l == 0) ? (1.41421356237309515f * 30.0f * INV2PI) : INV2PI;
        const float v = ((l == 0) ? W0[rem] : Wh[i - 65536]) * sc;
        const int jt = j >> 4, kt = k >> 5, q = (k >> 3) & 3, r = j & 15, t = k & 7;
        const int dst = (l << 16) + (((jt << 3) + kt) << 9) + (((q << 4) + r) << 3) + t;
        wb[dst] = f2bf(v);
    }
    if (i < 4096)
        wb[327680 + i] = (i < 512) ? f2bf(Wf[i]) : (unsigned short)0;
    if (i < 1280) {   // scaled bias table (f32)
        const int l = i >> 8, j = i & 255;
        const float sc = (l == 0) ? (30.0f * INV2PI) : INV2PI;
        float* bsc = (float*)(wb + 331776);
        bsc[i] = ((l == 0) ? b0[j] : bh[i - 256]) * sc;
    }
}

// ---------------- kernel 2: fused model ----------------
__global__ __launch_bounds__(256, 3) void siren_fused(
    const float* __restrict__ x, const float* __restrict__ scales,
    const float* __restrict__ Bm, const float* __restrict__ bfin,
    const unsigned short* __restrict__ wb, float* __restrict__ out) {

    __shared__ __align__(16) unsigned short A[BM * HD];

    const int tid  = threadIdx.x;
    const int lane = tid & 63;
    const int wid  = tid >> 6;          // wave 0..3 owns neurons wid*64..+63
    const int row0 = blockIdx.x * BM;
    const int arow = lane & 15;
    const int q    = lane >> 4;         // 0..3
    const int kq   = q * 8;
    const float* bsc = (const float*)(wb + 331776);

    // ---- preload layer-0 kt=0 W fragments (overlap Fourier stage) ----
    bf16x8 wfbuf[2][4];
    #pragma unroll
    for (int jt = 0; jt < 4; ++jt)
        wfbuf[0][jt] = *(const bf16x8*)(wb + (((wid * 4 + jt) << 3) << 9) + lane * 8);

    // ---- Fourier feature stage (fp32; sqrt2 folded into W0'; no fract) ----
    {
        const int r  = tid >> 2;            // 0..63
        const int c0 = (tid & 3) * 32;      // 32 freqs per thread
        const float* xr = x + (row0 + r) * 3;
        const float x0 = xr[0] * scales[0] * INV2PI;
        const float x1 = xr[1] * scales[1] * INV2PI;
        const float x2 = xr[2] * scales[2] * INV2PI;
        #pragma unroll
        for (int cc = 0; cc < 32; cc += 8) {
            const int c = c0 + cc;
            float sv[8], cv[8];
            #pragma unroll
            for (int t = 0; t < 8; ++t) {
                const float rev = x0 * Bm[c + t] + x1 * Bm[128 + c + t] + x2 * Bm[256 + c + t];
                sv[t] = __builtin_amdgcn_sinf(rev);   // |rev| < ~50 rev, in-domain
                cv[t] = __builtin_amdgcn_cosf(rev);
            }
            uint4 us, uc;
            us.x = pk2(sv[0], sv[1]); us.y = pk2(sv[2], sv[3]);
            us.z = pk2(sv[4], sv[5]); us.w = pk2(sv[6], sv[7]);
            uc.x = pk2(cv[0], cv[1]); uc.y = pk2(cv[2], cv[3]);
            uc.z = pk2(cv[4], cv[5]); uc.w = pk2(cv[6], cv[7]);
            *(uint4*)((char*)A + a_off(r, 2 * c))         = us;
            *(uint4*)((char*)A + a_off(r, 2 * (c + 128))) = uc;
        }
    }

    // ---- 5 dense layers ----
    #pragma unroll 1
    for (int layer = 0; layer < 5; ++layer) {
        const unsigned short* Wl = wb + (layer << 16);
        const float* bl = bsc + layer * HD;

        __syncthreads();   // bar1: h tile ready

        // acc initialized with the scaled bias (C-in = b') — r16 placement
        f32x4 acc[4][4];
        #pragma unroll
        for (int jt = 0; jt < 4; ++jt) {
            const float4 bv = *(const float4*)(bl + wid * 64 + jt * 16 + q * 4);
            #pragma unroll
            for (int rt = 0; rt < 4; ++rt) {
                acc[jt][rt][0] = bv.x; acc[jt][rt][1] = bv.y;
                acc[jt][rt][2] = bv.z; acc[jt][rt][3] = bv.w;
            }
        }

        #pragma unroll
        for (int kt = 0; kt < 8; ++kt) {
            const int cur = kt & 1, nxt = cur ^ 1;
            bf16x8 hf[4];
            #pragma unroll
            for (int rt = 0; rt < 4; ++rt)
                hf[rt] = *(const bf16x8*)((const char*)A +
                    a_off(rt * 16 + arow, kt * 64 + q * 16));
            if (kt < 7) {
                #pragma unroll
                for (int jt = 0; jt < 4; ++jt)
                    wfbuf[nxt][jt] = *(const bf16x8*)(Wl +
                        ((((wid * 4 + jt) << 3) + kt + 1) << 9) + lane * 8);
            }
            #pragma unroll
            for (int jt = 0; jt < 4; ++jt)
                #pragma unroll
                for (int rt = 0; rt < 4; ++rt)
                    acc[jt][rt] = __builtin_amdgcn_mfma_f32_16x16x32_bf16(
                        wfbuf[cur][jt], hf[rt], acc[jt][rt], 0, 0, 0);
        }

        // prefetch next layer's kt=0 W fragments BEFORE bar2: global->reg only,
        // latency overlaps the barrier wait + epilogue. wfbuf[0] is dead here
        // (kt=7 consumed wfbuf[1]) — zero added register pressure.
        if (layer < 4) {
            const unsigned short* Wn = wb + ((layer + 1) << 16);
            #pragma unroll
            for (int jt = 0; jt < 4; ++jt)
                wfbuf[0][jt] = *(const bf16x8*)(Wn + (((wid * 4 + jt) << 3) << 9) + lane * 8);
        }

        __syncthreads();   // bar2: all reads of h done; safe to overwrite

        // epilogue: h = sin(2*pi*acc) — bare v_sin + pack (bias/scale pre-folded)
        #pragma unroll
        for (int jt = 0; jt < 4; ++jt) {
            const int jj = wid * 64 + jt * 16 + q * 4;   // 4 consecutive neurons
            #pragma unroll
            for (int rt = 0; rt < 4; ++rt) {
                const int r = rt * 16 + arow;
                const float s0 = __builtin_amdgcn_sinf(acc[jt][rt][0]);
                const float s1 = __builtin_amdgcn_sinf(acc[jt][rt][1]);
                const float s2 = __builtin_amdgcn_sinf(acc[jt][rt][2]);
                const float s3 = __builtin_amdgcn_sinf(acc[jt][rt][3]);
                uint2 val;
                val.x = pk2(s0, s1);
                val.y = pk2(s2, s3);
                *(uint2*)((char*)A + a_off(r, jj * 2)) = val;
            }
        }
    }

    __syncthreads();   // final h ready

    // ---- final linear 256 -> 2, distributed: wave w handles rows w*16..+15 ----
    {
        const unsigned short* Wfp = wb + 327680;   // row-major [16][256], zero-padded
        f32x4 acc = (f32x4)(0.0f);
        #pragma unroll
        for (int kt = 0; kt < 8; ++kt) {
            const bf16x8 ff = *(const bf16x8*)(Wfp + arow * HD + kt * 32 + kq);
            const bf16x8 hf = *(const bf16x8*)((const char*)A +
                a_off(wid * 16 + arow, kt * 64 + q * 16));
            acc = __builtin_amdgcn_mfma_f32_16x16x32_bf16(ff, hf, acc, 0, 0, 0);
        }
        if (q == 0) {   // lanes 0-15 hold D rows j=0..3; j=0,1 are the two outputs
            const int rg = row0 + wid * 16 + arow;
            float2 o;
            o.x = acc[0] + bfin[0];
            o.y = acc[1] + bfin[1];
            *(float2*)(out + rg * 2) = o;
        }
    }
}

extern "C" void kernel_launch(void* const* d_in, const int* in_sizes, int n_in,
                              void* d_out, int out_size, void* d_ws, size_t ws_size,
                              hipStream_t stream) {
    (void)in_sizes; (void)n_in; (void)out_size; (void)ws_size;
    const float* x      = (const float*)d_in[0];
    const float* scales = (const float*)d_in[1];
    const float* Bm     = (const float*)d_in[2];
    const float* W0     = (const float*)d_in[3];
    const float* b0     = (const float*)d_in[4];
    const float* Wh     = (const float*)d_in[5];
    const float* bh     = (const float*)d_in[6];
    const float* Wf     = (const float*)d_in[7];
    const float* bf     = (const float*)d_in[8];
    unsigned short* wb  = (unsigned short*)d_ws;   // needs 668672 B

    hipLaunchKernelGGL(convert_w, dim3(1280), dim3(256), 0, stream,
                       W0, Wh, Wf, b0, bh, wb);
    hipLaunchKernelGGL(siren_fused, dim3(NTOTAL / BM), dim3(256), 0, stream,
                       x, scales, Bm, bf, wb, (float*)d_out);
}